// Round 4
// baseline (211.659 us; speedup 1.0000x reference)
//
#include <hip/hip_runtime.h>

// Fused causal MHA: B=2, N=2048, D=1024, H=16, dh=64
// Round 4: round-3 attn structure + explicit LDS ordering fences around the
// P bounce (ds_write -> ds_read same-row cross-lane data was racy: compiler
// could omit the lgkmcnt wait since per-lane write/read ranges don't overlap
// for g>0). setprio removed this round to minimize unknowns.

typedef __bf16 bf16x8 __attribute__((ext_vector_type(8)));
typedef float f32x4 __attribute__((ext_vector_type(4)));

#define MFMA16(a, b, c) __builtin_amdgcn_mfma_f32_16x16x32_bf16((a), (b), (c), 0, 0, 0)

// Order LDS traffic: drain DS queue and pin the schedule point.
#define LDS_FENCE()                                   \
  do {                                                \
    asm volatile("s_waitcnt lgkmcnt(0)" ::: "memory");\
    __builtin_amdgcn_sched_barrier(0);                \
  } while (0)

__device__ __forceinline__ unsigned short f2bf(float f) {
  __bf16 h = (__bf16)f;                 // hardware RNE cvt
  return *(unsigned short*)&h;
}

// ---------------- elementwise cast f32 -> bf16 ------------------------------
__global__ void cast_bf16_kernel(const float* __restrict__ in,
                                 unsigned short* __restrict__ out, int n4) {
  int i = blockIdx.x * blockDim.x + threadIdx.x;
  if (i >= n4) return;
  float4 v = ((const float4*)in)[i];
  ushort4 o;
  o.x = f2bf(v.x); o.y = f2bf(v.y); o.z = f2bf(v.z); o.w = f2bf(v.w);
  ((ushort4*)out)[i] = o;
}

// ------- transpose + cast: f32 [R][C] -> bf16 [C][R], scale first rows ------
__global__ void transpose_cast_kernel(const float* __restrict__ in,
                                      unsigned short* __restrict__ out,
                                      int R, int C, int scale_rows) {
  __shared__ float tile[32][33];
  const int bx = blockIdx.x, by = blockIdx.y;
  const int tx = threadIdx.x, ty = threadIdx.y;
#pragma unroll
  for (int i = ty; i < 32; i += 8)
    tile[i][tx] = in[(size_t)(by * 32 + i) * C + bx * 32 + tx];
  __syncthreads();
#pragma unroll
  for (int i = ty; i < 32; i += 8) {
    const int orow = bx * 32 + i;
    const float s = (orow < scale_rows) ? 0.18033688f : 1.0f;  // 0.125*log2e
    out[(size_t)orow * R + by * 32 + tx] = f2bf(tile[tx][i] * s);
  }
}

// ------- transpose V region of qkv (bf16) into vT[b][h*64+dim][n] -----------
__global__ void transpose_v_kernel(const unsigned short* __restrict__ qkv,
                                   unsigned short* __restrict__ vT) {
  __shared__ unsigned short tile[32][33];
  const int b = blockIdx.z, bx = blockIdx.x, by = blockIdx.y;
  const int tx = threadIdx.x, ty = threadIdx.y;
#pragma unroll
  for (int i = ty; i < 32; i += 8)
    tile[i][tx] = qkv[(size_t)(b * 2048 + by * 32 + i) * 3072 + 2048 + bx * 32 + tx];
  __syncthreads();
#pragma unroll
  for (int i = ty; i < 32; i += 8)
    vT[((size_t)b * 1024 + bx * 32 + i) * 2048 + by * 32 + tx] = tile[tx][i];
}

// ---------------- 128x128 bf16 GEMM: C = A[M][K] * BT[Nc][K]^T --------------
template <int OUT_BF16>
__global__ __launch_bounds__(256) void gemm128_kernel(
    const unsigned short* __restrict__ A,   // [M][K] bf16
    const unsigned short* __restrict__ BT,  // [Nc][K] bf16
    void* __restrict__ Cp, int M, int Nc, int K) {
  __shared__ unsigned short lA[128 * 32];
  __shared__ unsigned short lB[128 * 32];
  const int t = threadIdx.x;
  const int l = t & 63, g = l >> 4, c = l & 15;
  const int w = t >> 6;
  const int wm = (w >> 1) * 64, wn = (w & 1) * 64;
  const int bm = blockIdx.y * 128, bn = blockIdx.x * 128;

  const int i0 = t, i1 = 256 + t;
  const unsigned short* ga0 = A + (size_t)(bm + (i0 >> 2)) * K + (i0 & 3) * 8;
  const unsigned short* ga1 = A + (size_t)(bm + (i1 >> 2)) * K + (i1 & 3) * 8;
  const unsigned short* gb0 = BT + (size_t)(bn + (i0 >> 2)) * K + (i0 & 3) * 8;
  const unsigned short* gb1 = BT + (size_t)(bn + (i1 >> 2)) * K + (i1 & 3) * 8;
  unsigned short* la0 = lA + (i0 & ~63) * 8;
  unsigned short* la1 = lA + (i1 & ~63) * 8;
  unsigned short* lb0 = lB + (i0 & ~63) * 8;
  unsigned short* lb1 = lB + (i1 & ~63) * 8;

  f32x4 acc[4][4] = {};

  for (int kk = 0; kk < K; kk += 32) {
    __syncthreads();
    __builtin_amdgcn_global_load_lds(
        (const __attribute__((address_space(1))) void*)(ga0 + kk),
        (__attribute__((address_space(3))) void*)la0, 16, 0, 0);
    __builtin_amdgcn_global_load_lds(
        (const __attribute__((address_space(1))) void*)(ga1 + kk),
        (__attribute__((address_space(3))) void*)la1, 16, 0, 0);
    __builtin_amdgcn_global_load_lds(
        (const __attribute__((address_space(1))) void*)(gb0 + kk),
        (__attribute__((address_space(3))) void*)lb0, 16, 0, 0);
    __builtin_amdgcn_global_load_lds(
        (const __attribute__((address_space(1))) void*)(gb1 + kk),
        (__attribute__((address_space(3))) void*)lb1, 16, 0, 0);
    __syncthreads();

    bf16x8 af[4], bfr[4];
#pragma unroll
    for (int mi = 0; mi < 4; ++mi)
      af[mi] = *(const bf16x8*)(lA + (wm + mi * 16 + c) * 32 + g * 8);
#pragma unroll
    for (int ni = 0; ni < 4; ++ni)
      bfr[ni] = *(const bf16x8*)(lB + (wn + ni * 16 + c) * 32 + g * 8);
#pragma unroll
    for (int mi = 0; mi < 4; ++mi)
#pragma unroll
      for (int ni = 0; ni < 4; ++ni)
        acc[mi][ni] = MFMA16(af[mi], bfr[ni], acc[mi][ni]);
  }

  if (OUT_BF16) {
    unsigned short* Cc = (unsigned short*)Cp;
#pragma unroll
    for (int mi = 0; mi < 4; ++mi)
#pragma unroll
      for (int r = 0; r < 4; ++r) {
        const int gr = bm + wm + mi * 16 + g * 4 + r;
#pragma unroll
        for (int ni = 0; ni < 4; ++ni)
          Cc[(size_t)gr * Nc + bn + wn + ni * 16 + c] = f2bf(acc[mi][ni][r]);
      }
  } else {
    float* Cf = (float*)Cp;
#pragma unroll
    for (int mi = 0; mi < 4; ++mi)
#pragma unroll
      for (int r = 0; r < 4; ++r) {
        const int gr = bm + wm + mi * 16 + g * 4 + r;
#pragma unroll
        for (int ni = 0; ni < 4; ++ni)
          Cf[(size_t)gr * Nc + bn + wn + ni * 16 + c] = acc[mi][ni][r];
      }
  }
}

// ---------------- flash attention (causal, swapped QK^T) --------------------
// 512 blocks (XCD-swizzled), 4 independent waves x 16 q-rows, tile pair
// {31-bx, bx}. Full 64-kv blocks mask-free; diagonal at 32-kv granularity
// with masks. Vote-only defer-max; per-lane partial denominator; K reg
// double-buffer. P bounce through per-wave LDS with explicit fences.
__global__ __launch_bounds__(256) void attn_kernel(
    const unsigned short* __restrict__ qkv,  // [4096][3072] bf16 (Q|K|V)
    const unsigned short* __restrict__ vT,   // [2][1024][2048] bf16
    unsigned short* __restrict__ aout) {     // [4096][1024] bf16
  const int t = threadIdx.x, w = t >> 6, l = t & 63, g = l >> 4, c = l & 15;
  const int g4 = g * 4;

  const int id0 = blockIdx.x;
  const int id = (id0 & 7) * 64 + (id0 >> 3);   // XCD-bijective: 4 heads/XCD
  const int bx = id & 15, bh = id >> 4;
  const int b = bh >> 4, h = bh & 15;

  __shared__ __align__(16) unsigned short pl[4][16][72];  // 144B rows

  const unsigned short* Qbase = qkv + (size_t)b * 2048 * 3072 + h * 64;
  const unsigned short* Kb = Qbase + 1024;
  const unsigned short* Vb = vT + ((size_t)b * 1024 + h * 64) * 2048;

#define KFRAG(row, half) (*(const bf16x8*)(Kb + (size_t)(row) * 3072 + (half) * 32 + g * 8))
#define VFRAG(dt, kvoff) (*(const bf16x8*)(Vb + (size_t)((dt) * 16 + c) * 2048 + (kvoff) + g * 8))

#pragma unroll 1
  for (int pass = 0; pass < 2; ++pass) {
    const int tile = pass ? bx : (31 - bx);
    const int q0 = tile * 64 + w * 16;
    const int qc = q0 + c;

    const bf16x8 bq0 = *(const bf16x8*)(Qbase + (size_t)qc * 3072 + g * 8);
    const bf16x8 bq1 = *(const bf16x8*)(Qbase + (size_t)qc * 3072 + 32 + g * 8);

    f32x4 o[4] = {};
    float m_c = -__builtin_inff(), llp = 0.f;

    bf16x8 ka[8];   // current 64-kv block K frags
    if (tile > 0) {
#pragma unroll
      for (int n = 0; n < 4; ++n) {
        ka[2 * n] = KFRAG(16 * n + c, 0);
        ka[2 * n + 1] = KFRAG(16 * n + c, 1);
      }
    }

#pragma unroll 1
    for (int jb = 0; jb < tile; ++jb) {
      const int kb = jb * 64;
      bf16x8 bv[2][4];
#pragma unroll
      for (int ks = 0; ks < 2; ++ks)
#pragma unroll
        for (int dt = 0; dt < 4; ++dt)
          bv[ks][dt] = VFRAG(dt, kb + ks * 32);

      f32x4 s[4] = {};
#pragma unroll
      for (int n = 0; n < 4; ++n) {
        s[n] = MFMA16(ka[2 * n], bq0, s[n]);
        s[n] = MFMA16(ka[2 * n + 1], bq1, s[n]);
      }

      // prefetch next block's K (always in-bounds rows)
      bf16x8 kn[8];
#pragma unroll
      for (int n = 0; n < 4; ++n) {
        kn[2 * n] = KFRAG(kb + 64 + 16 * n + c, 0);
        kn[2 * n + 1] = KFRAG(kb + 64 + 16 * n + c, 1);
      }

      // ---- softmax, mask-free fast path (exp2 domain) ----
      float m01 = fmaxf(fmaxf(s[0][0], s[0][1]), fmaxf(s[0][2], s[0][3]));
      float m23 = fmaxf(fmaxf(s[1][0], s[1][1]), fmaxf(s[1][2], s[1][3]));
      float m45 = fmaxf(fmaxf(s[2][0], s[2][1]), fmaxf(s[2][2], s[2][3]));
      float m67 = fmaxf(fmaxf(s[3][0], s[3][1]), fmaxf(s[3][2], s[3][3]));
      const float vml = fmaxf(fmaxf(m01, m23), fmaxf(m45, m67));

      if (!__all(vml - m_c <= 5.0f)) {   // rare: rescale
        float vm = vml;
        vm = fmaxf(vm, __shfl_xor(vm, 16));
        vm = fmaxf(vm, __shfl_xor(vm, 32));
        const float mn = fmaxf(m_c, vm);
        const float al = exp2f(m_c - mn);
        m_c = mn;
        llp *= al;
#pragma unroll
        for (int r = 0; r < 4; ++r) {
          const float alr = __shfl(al, g4 + r);
          o[0][r] *= alr; o[1][r] *= alr; o[2][r] *= alr; o[3][r] *= alr;
        }
      }

#pragma unroll
      for (int n = 0; n < 4; ++n)
#pragma unroll
        for (int r = 0; r < 4; ++r)
          s[n][r] = exp2f(s[n][r] - m_c);

      llp += ((s[0][0] + s[0][1]) + (s[0][2] + s[0][3])) +
             ((s[1][0] + s[1][1]) + (s[1][2] + s[1][3])) +
             ((s[2][0] + s[2][1]) + (s[2][2] + s[2][3])) +
             ((s[3][0] + s[3][1]) + (s[3][2] + s[3][3]));

      LDS_FENCE();   // prior pa reads complete before overwrite
#pragma unroll
      for (int n = 0; n < 4; ++n) {
        ushort4 pw;
        pw.x = f2bf(s[n][0]); pw.y = f2bf(s[n][1]);
        pw.z = f2bf(s[n][2]); pw.w = f2bf(s[n][3]);
        *(ushort4*)&pl[w][c][n * 16 + g4] = pw;
      }
      LDS_FENCE();   // P stores visible before cross-lane fragment read
      const bf16x8 pa0 = *(const bf16x8*)&pl[w][c][g * 8];
      const bf16x8 pa1 = *(const bf16x8*)&pl[w][c][32 + g * 8];

#pragma unroll
      for (int dt = 0; dt < 4; ++dt) {
        o[dt] = MFMA16(pa0, bv[0][dt], o[dt]);
        o[dt] = MFMA16(pa1, bv[1][dt], o[dt]);
      }

#pragma unroll
      for (int i = 0; i < 8; ++i) ka[i] = kn[i];
    }

    // ---- diagonal: 1-2 masked 32-kv blocks ----
    const int ndiag = 1 + (w >> 1);
#pragma unroll 1
    for (int j = 0; j < ndiag; ++j) {
      const int kb = tile * 64 + j * 32;
      const bf16x8 k00 = KFRAG(kb + c, 0), k01 = KFRAG(kb + c, 1);
      const bf16x8 k10 = KFRAG(kb + 16 + c, 0), k11 = KFRAG(kb + 16 + c, 1);
      const bf16x8 bv0 = VFRAG(0, kb), bv1 = VFRAG(1, kb);
      const bf16x8 bv2 = VFRAG(2, kb), bv3 = VFRAG(3, kb);

      f32x4 s0 = {}, s1 = {};
      s0 = MFMA16(k00, bq0, s0);
      s0 = MFMA16(k01, bq1, s0);
      s1 = MFMA16(k10, bq0, s1);
      s1 = MFMA16(k11, bq1, s1);

      float v0[4], v1[4];
#pragma unroll
      for (int r = 0; r < 4; ++r) {
        v0[r] = (kb + g4 + r <= qc) ? s0[r] : -__builtin_inff();
        v1[r] = (kb + 16 + g4 + r <= qc) ? s1[r] : -__builtin_inff();
      }
      const float vml = fmaxf(fmaxf(fmaxf(v0[0], v0[1]), fmaxf(v0[2], v0[3])),
                              fmaxf(fmaxf(v1[0], v1[1]), fmaxf(v1[2], v1[3])));
      if (!__all(vml - m_c <= 5.0f)) {
        float vm = vml;
        vm = fmaxf(vm, __shfl_xor(vm, 16));
        vm = fmaxf(vm, __shfl_xor(vm, 32));
        const float mn = fmaxf(m_c, vm);
        const float al = exp2f(m_c - mn);
        m_c = mn;
        llp *= al;
#pragma unroll
        for (int r = 0; r < 4; ++r) {
          const float alr = __shfl(al, g4 + r);
          o[0][r] *= alr; o[1][r] *= alr; o[2][r] *= alr; o[3][r] *= alr;
        }
      }
      float p0[4], p1[4];
#pragma unroll
      for (int r = 0; r < 4; ++r) {
        p0[r] = exp2f(v0[r] - m_c);
        p1[r] = exp2f(v1[r] - m_c);
      }
      llp += ((p0[0] + p0[1]) + (p0[2] + p0[3])) +
             ((p1[0] + p1[1]) + (p1[2] + p1[3]));

      LDS_FENCE();
      ushort4 pw;
      pw.x = f2bf(p0[0]); pw.y = f2bf(p0[1]); pw.z = f2bf(p0[2]); pw.w = f2bf(p0[3]);
      *(ushort4*)&pl[w][c][g4] = pw;
      pw.x = f2bf(p1[0]); pw.y = f2bf(p1[1]); pw.z = f2bf(p1[2]); pw.w = f2bf(p1[3]);
      *(ushort4*)&pl[w][c][16 + g4] = pw;
      LDS_FENCE();
      const bf16x8 pa = *(const bf16x8*)&pl[w][c][g * 8];

      o[0] = MFMA16(pa, bv0, o[0]);
      o[1] = MFMA16(pa, bv1, o[1]);
      o[2] = MFMA16(pa, bv2, o[2]);
      o[3] = MFMA16(pa, bv3, o[3]);
    }

    // ---- finalize: reduce per-lane partial denominators across g ----
    float ll = llp;
    ll += __shfl_xor(ll, 16);
    ll += __shfl_xor(ll, 32);
    const float inv = 1.0f / ll;
#pragma unroll
    for (int r = 0; r < 4; ++r) {
      const float invr = __shfl(inv, g4 + r);
      const size_t row = (size_t)(b * 2048 + q0 + g4 + r);
#pragma unroll
      for (int dt = 0; dt < 4; ++dt)
        aout[row * 1024 + h * 64 + dt * 16 + c] = f2bf(o[dt][r] * invr);
    }
  }
#undef KFRAG
#undef VFRAG
}

// ---------------------------------------------------------------------------
extern "C" void kernel_launch(void* const* d_in, const int* in_sizes, int n_in,
                              void* d_out, int out_size, void* d_ws, size_t ws_size,
                              hipStream_t stream) {
  const float* x = (const float*)d_in[0];      // [2,2048,1024]
  const float* wqkv = (const float*)d_in[1];   // [1024,3072]
  const float* wout = (const float*)d_in[2];   // [1024,1024]
  float* out = (float*)d_out;                  // [2,2048,1024] f32

  unsigned short* ws = (unsigned short*)d_ws;
  unsigned short* xb = ws;                                  // 4096*1024
  unsigned short* wqkvT = xb + (size_t)4096 * 1024;         // 3072*1024
  unsigned short* woutT = wqkvT + (size_t)3072 * 1024;      // 1024*1024
  unsigned short* qkv = woutT + (size_t)1024 * 1024;        // 4096*3072
  unsigned short* vT = qkv + (size_t)4096 * 3072;           // 2*1024*2048
  unsigned short* aout = vT + (size_t)2 * 1024 * 2048;      // 4096*1024

  cast_bf16_kernel<<<4096, 256, 0, stream>>>(x, xb, 4096 * 1024 / 4);
  transpose_cast_kernel<<<dim3(96, 32), dim3(32, 8), 0, stream>>>(wqkv, wqkvT, 1024, 3072, 1024);
  transpose_cast_kernel<<<dim3(32, 32), dim3(32, 8), 0, stream>>>(wout, woutT, 1024, 1024, 0);
  gemm128_kernel<1><<<dim3(24, 32), 256, 0, stream>>>(xb, wqkvT, qkv, 4096, 3072, 1024);
  transpose_v_kernel<<<dim3(32, 64, 2), dim3(32, 8), 0, stream>>>(qkv, vT);
  attn_kernel<<<512, 256, 0, stream>>>(qkv, vT, aout);
  gemm128_kernel<0><<<dim3(8, 32), 256, 0, stream>>>(aout, woutT, out, 4096, 1024, 1024);
}

// Round 5
// 136.058 us; speedup vs baseline: 1.5557x; 1.5557x over previous
//
#include <hip/hip_runtime.h>

// Fused causal MHA: B=2, N=2048, D=1024, H=16, dh=64
// Round 5: attn latency fix — K/V LDS staging (double-buffered,
// global_load_lds w16, XOR-swizzled source+read, linear dest), 1024 unpaired
// blocks big-first + bh-clustered per XCD, barriers only in uniform loop.

typedef __bf16 bf16x8 __attribute__((ext_vector_type(8)));
typedef float f32x4 __attribute__((ext_vector_type(4)));

#define MFMA16(a, b, c) __builtin_amdgcn_mfma_f32_16x16x32_bf16((a), (b), (c), 0, 0, 0)

// Order LDS traffic: drain DS queue and pin the schedule point.
#define LDS_FENCE()                                   \
  do {                                                \
    asm volatile("s_waitcnt lgkmcnt(0)" ::: "memory");\
    __builtin_amdgcn_sched_barrier(0);                \
  } while (0)

__device__ __forceinline__ unsigned short f2bf(float f) {
  __bf16 h = (__bf16)f;                 // hardware RNE cvt
  return *(unsigned short*)&h;
}

// ---------------- elementwise cast f32 -> bf16 ------------------------------
__global__ void cast_bf16_kernel(const float* __restrict__ in,
                                 unsigned short* __restrict__ out, int n4) {
  int i = blockIdx.x * blockDim.x + threadIdx.x;
  if (i >= n4) return;
  float4 v = ((const float4*)in)[i];
  ushort4 o;
  o.x = f2bf(v.x); o.y = f2bf(v.y); o.z = f2bf(v.z); o.w = f2bf(v.w);
  ((ushort4*)out)[i] = o;
}

// ------- transpose + cast: f32 [R][C] -> bf16 [C][R], scale first rows ------
__global__ void transpose_cast_kernel(const float* __restrict__ in,
                                      unsigned short* __restrict__ out,
                                      int R, int C, int scale_rows) {
  __shared__ float tile[32][33];
  const int bx = blockIdx.x, by = blockIdx.y;
  const int tx = threadIdx.x, ty = threadIdx.y;
#pragma unroll
  for (int i = ty; i < 32; i += 8)
    tile[i][tx] = in[(size_t)(by * 32 + i) * C + bx * 32 + tx];
  __syncthreads();
#pragma unroll
  for (int i = ty; i < 32; i += 8) {
    const int orow = bx * 32 + i;
    const float s = (orow < scale_rows) ? 0.18033688f : 1.0f;  // 0.125*log2e
    out[(size_t)orow * R + by * 32 + tx] = f2bf(tile[tx][i] * s);
  }
}

// ------- transpose V region of qkv (bf16) into vT[b][h*64+dim][n] -----------
__global__ void transpose_v_kernel(const unsigned short* __restrict__ qkv,
                                   unsigned short* __restrict__ vT) {
  __shared__ unsigned short tile[32][33];
  const int b = blockIdx.z, bx = blockIdx.x, by = blockIdx.y;
  const int tx = threadIdx.x, ty = threadIdx.y;
#pragma unroll
  for (int i = ty; i < 32; i += 8)
    tile[i][tx] = qkv[(size_t)(b * 2048 + by * 32 + i) * 3072 + 2048 + bx * 32 + tx];
  __syncthreads();
#pragma unroll
  for (int i = ty; i < 32; i += 8)
    vT[((size_t)b * 1024 + bx * 32 + i) * 2048 + by * 32 + tx] = tile[tx][i];
}

// ---------------- 128x128 bf16 GEMM: C = A[M][K] * BT[Nc][K]^T --------------
template <int OUT_BF16>
__global__ __launch_bounds__(256) void gemm128_kernel(
    const unsigned short* __restrict__ A,   // [M][K] bf16
    const unsigned short* __restrict__ BT,  // [Nc][K] bf16
    void* __restrict__ Cp, int M, int Nc, int K) {
  __shared__ unsigned short lA[128 * 32];
  __shared__ unsigned short lB[128 * 32];
  const int t = threadIdx.x;
  const int l = t & 63, g = l >> 4, c = l & 15;
  const int w = t >> 6;
  const int wm = (w >> 1) * 64, wn = (w & 1) * 64;
  const int bm = blockIdx.y * 128, bn = blockIdx.x * 128;

  const int i0 = t, i1 = 256 + t;
  const unsigned short* ga0 = A + (size_t)(bm + (i0 >> 2)) * K + (i0 & 3) * 8;
  const unsigned short* ga1 = A + (size_t)(bm + (i1 >> 2)) * K + (i1 & 3) * 8;
  const unsigned short* gb0 = BT + (size_t)(bn + (i0 >> 2)) * K + (i0 & 3) * 8;
  const unsigned short* gb1 = BT + (size_t)(bn + (i1 >> 2)) * K + (i1 & 3) * 8;
  unsigned short* la0 = lA + (i0 & ~63) * 8;
  unsigned short* la1 = lA + (i1 & ~63) * 8;
  unsigned short* lb0 = lB + (i0 & ~63) * 8;
  unsigned short* lb1 = lB + (i1 & ~63) * 8;

  f32x4 acc[4][4] = {};

  for (int kk = 0; kk < K; kk += 32) {
    __syncthreads();
    __builtin_amdgcn_global_load_lds(
        (const __attribute__((address_space(1))) void*)(ga0 + kk),
        (__attribute__((address_space(3))) void*)la0, 16, 0, 0);
    __builtin_amdgcn_global_load_lds(
        (const __attribute__((address_space(1))) void*)(ga1 + kk),
        (__attribute__((address_space(3))) void*)la1, 16, 0, 0);
    __builtin_amdgcn_global_load_lds(
        (const __attribute__((address_space(1))) void*)(gb0 + kk),
        (__attribute__((address_space(3))) void*)lb0, 16, 0, 0);
    __builtin_amdgcn_global_load_lds(
        (const __attribute__((address_space(1))) void*)(gb1 + kk),
        (__attribute__((address_space(3))) void*)lb1, 16, 0, 0);
    __syncthreads();

    bf16x8 af[4], bfr[4];
#pragma unroll
    for (int mi = 0; mi < 4; ++mi)
      af[mi] = *(const bf16x8*)(lA + (wm + mi * 16 + c) * 32 + g * 8);
#pragma unroll
    for (int ni = 0; ni < 4; ++ni)
      bfr[ni] = *(const bf16x8*)(lB + (wn + ni * 16 + c) * 32 + g * 8);
#pragma unroll
    for (int mi = 0; mi < 4; ++mi)
#pragma unroll
      for (int ni = 0; ni < 4; ++ni)
        acc[mi][ni] = MFMA16(af[mi], bfr[ni], acc[mi][ni]);
  }

  if (OUT_BF16) {
    unsigned short* Cc = (unsigned short*)Cp;
#pragma unroll
    for (int mi = 0; mi < 4; ++mi)
#pragma unroll
      for (int r = 0; r < 4; ++r) {
        const int gr = bm + wm + mi * 16 + g * 4 + r;
#pragma unroll
        for (int ni = 0; ni < 4; ++ni)
          Cc[(size_t)gr * Nc + bn + wn + ni * 16 + c] = f2bf(acc[mi][ni][r]);
      }
  } else {
    float* Cf = (float*)Cp;
#pragma unroll
    for (int mi = 0; mi < 4; ++mi)
#pragma unroll
      for (int r = 0; r < 4; ++r) {
        const int gr = bm + wm + mi * 16 + g * 4 + r;
#pragma unroll
        for (int ni = 0; ni < 4; ++ni)
          Cf[(size_t)gr * Nc + bn + wn + ni * 16 + c] = acc[mi][ni][r];
      }
  }
}

// ---------------- flash attention (causal, swapped QK^T) --------------------
// 1024 blocks: one (bh, q-tile) each; big tiles dispatched first, 4 heads
// clustered per XCD. 4 waves x 16 q-rows. Full 64-kv blocks: K/V staged in
// double-buffered LDS via global_load_lds (XOR-swizzled src + read, linear
// dest), one barrier per iter (uniform trip count). Diagonal: direct global
// frags, barrier-free (waves diverge). Vote-only defer-max; per-lane partial
// denominator; P bounce through per-wave LDS with fences.
__global__ __launch_bounds__(256) void attn_kernel(
    const unsigned short* __restrict__ qkv,  // [4096][3072] bf16 (Q|K|V)
    const unsigned short* __restrict__ vT,   // [2][1024][2048] bf16
    unsigned short* __restrict__ aout) {     // [4096][1024] bf16
  const int t = threadIdx.x, w = t >> 6, l = t & 63, g = l >> 4, c = l & 15;
  const int g4 = g * 4, c7 = c & 7;

  // decode: xcd-clustered heads, descending tile within each XCD sequence
  const int id0 = blockIdx.x;              // 0..1023
  const int xcd = id0 & 7, pos = id0 >> 3; // pos 0..127
  const int bh = xcd * 4 + (pos & 3);      // 4 heads per XCD
  const int tile = 31 - (pos >> 2);        // big tiles first
  const int b = bh >> 4, h = bh & 15;

  __shared__ __align__(16) unsigned short lK[2][64][64];  // 16 KB
  __shared__ __align__(16) unsigned short lV[2][64][64];  // 16 KB
  __shared__ __align__(16) unsigned short pl[4][16][72];  // 9 KB P bounce

  const unsigned short* Qbase = qkv + (size_t)b * 2048 * 3072 + h * 64;
  const unsigned short* Kb = Qbase + 1024;
  const unsigned short* Vb = vT + ((size_t)b * 1024 + h * 64) * 2048;

#define KFRAG(row, half) (*(const bf16x8*)(Kb + (size_t)(row) * 3072 + (half) * 32 + g * 8))
#define VFRAG(dt, kvoff) (*(const bf16x8*)(Vb + (size_t)((dt) * 16 + c) * 2048 + (kvoff) + g * 8))

  // stage 64-kv block kb_: K rows kb_..kb_+63 (64 dims), V dims 0..63
  // (cols kb_..kb_+63). Linear LDS dest; source chunk XOR-swizzled so that
  // physical chunk ch holds logical chunk ch^(row&7).
#define STAGE(dK, dV, kb_)                                                    \
  do {                                                                        \
    _Pragma("unroll")                                                         \
    for (int q = 0; q < 2; ++q) {                                             \
      const int idx = q * 256 + t;                                            \
      const int row = idx >> 3, ch = idx & 7;                                 \
      const int sc = (ch ^ (row & 7)) * 8;                                    \
      __builtin_amdgcn_global_load_lds(                                       \
          (const __attribute__((address_space(1))) void*)(                    \
              Kb + (size_t)(kb_ + row) * 3072 + sc),                          \
          (__attribute__((address_space(3))) void*)(                          \
              &(dK)[0][0] + (idx & ~63) * 8), 16, 0, 0);                      \
      __builtin_amdgcn_global_load_lds(                                       \
          (const __attribute__((address_space(1))) void*)(                    \
              Vb + (size_t)row * 2048 + (kb_) + sc),                          \
          (__attribute__((address_space(3))) void*)(                          \
              &(dV)[0][0] + (idx & ~63) * 8), 16, 0, 0);                      \
    }                                                                         \
  } while (0)

  const int q0 = tile * 64 + w * 16;
  const int qc = q0 + c;

  const bf16x8 bq0 = *(const bf16x8*)(Qbase + (size_t)qc * 3072 + g * 8);
  const bf16x8 bq1 = *(const bf16x8*)(Qbase + (size_t)qc * 3072 + 32 + g * 8);

  f32x4 o[4] = {};
  float m_c = -__builtin_inff(), llp = 0.f;

  if (tile > 0) {
    STAGE(lK[0], lV[0], 0);
    int cur = 0;
#pragma unroll 1
    for (int jb = 0; jb < tile; ++jb) {
      __syncthreads();   // drains this block's stage (vmcnt) + prev compute
      if (jb + 1 < tile) STAGE(lK[cur ^ 1], lV[cur ^ 1], (jb + 1) * 64);

      const unsigned short* lk = &lK[cur][0][0];
      const unsigned short* lv = &lV[cur][0][0];

      // K frags: row 16n+c, logical chunk half*4+g -> phys ^(c&7)
      bf16x8 ka[8];
#pragma unroll
      for (int n = 0; n < 4; ++n) {
        ka[2 * n]     = *(const bf16x8*)(lk + (16 * n + c) * 64 + ((g ^ c7) * 8));
        ka[2 * n + 1] = *(const bf16x8*)(lk + (16 * n + c) * 64 + (((4 + g) ^ c7) * 8));
      }
      // V frags: dim dt*16+c, logical chunk ks*4+g
      bf16x8 bv[2][4];
#pragma unroll
      for (int ks = 0; ks < 2; ++ks)
#pragma unroll
        for (int dt = 0; dt < 4; ++dt)
          bv[ks][dt] = *(const bf16x8*)(lv + (dt * 16 + c) * 64 + (((ks * 4 + g) ^ c7) * 8));

      f32x4 s[4] = {};
#pragma unroll
      for (int n = 0; n < 4; ++n) {
        s[n] = MFMA16(ka[2 * n], bq0, s[n]);
        s[n] = MFMA16(ka[2 * n + 1], bq1, s[n]);
      }

      // ---- softmax, mask-free fast path (exp2 domain) ----
      float m01 = fmaxf(fmaxf(s[0][0], s[0][1]), fmaxf(s[0][2], s[0][3]));
      float m23 = fmaxf(fmaxf(s[1][0], s[1][1]), fmaxf(s[1][2], s[1][3]));
      float m45 = fmaxf(fmaxf(s[2][0], s[2][1]), fmaxf(s[2][2], s[2][3]));
      float m67 = fmaxf(fmaxf(s[3][0], s[3][1]), fmaxf(s[3][2], s[3][3]));
      const float vml = fmaxf(fmaxf(m01, m23), fmaxf(m45, m67));

      if (!__all(vml - m_c <= 5.0f)) {   // rare: rescale
        float vm = vml;
        vm = fmaxf(vm, __shfl_xor(vm, 16));
        vm = fmaxf(vm, __shfl_xor(vm, 32));
        const float mn = fmaxf(m_c, vm);
        const float al = exp2f(m_c - mn);
        m_c = mn;
        llp *= al;
#pragma unroll
        for (int r = 0; r < 4; ++r) {
          const float alr = __shfl(al, g4 + r);
          o[0][r] *= alr; o[1][r] *= alr; o[2][r] *= alr; o[3][r] *= alr;
        }
      }

#pragma unroll
      for (int n = 0; n < 4; ++n)
#pragma unroll
        for (int r = 0; r < 4; ++r)
          s[n][r] = exp2f(s[n][r] - m_c);

      llp += ((s[0][0] + s[0][1]) + (s[0][2] + s[0][3])) +
             ((s[1][0] + s[1][1]) + (s[1][2] + s[1][3])) +
             ((s[2][0] + s[2][1]) + (s[2][2] + s[2][3])) +
             ((s[3][0] + s[3][1]) + (s[3][2] + s[3][3]));

      LDS_FENCE();   // prior pa reads complete before overwrite
#pragma unroll
      for (int n = 0; n < 4; ++n) {
        ushort4 pw;
        pw.x = f2bf(s[n][0]); pw.y = f2bf(s[n][1]);
        pw.z = f2bf(s[n][2]); pw.w = f2bf(s[n][3]);
        *(ushort4*)&pl[w][c][n * 16 + g4] = pw;
      }
      LDS_FENCE();   // P stores visible before cross-lane fragment read
      const bf16x8 pa0 = *(const bf16x8*)&pl[w][c][g * 8];
      const bf16x8 pa1 = *(const bf16x8*)&pl[w][c][32 + g * 8];

#pragma unroll
      for (int dt = 0; dt < 4; ++dt) {
        o[dt] = MFMA16(pa0, bv[0][dt], o[dt]);
        o[dt] = MFMA16(pa1, bv[1][dt], o[dt]);
      }
      cur ^= 1;
    }
  }

  // ---- diagonal: 1-2 masked 32-kv blocks, direct global, barrier-free ----
  const int ndiag = 1 + (w >> 1);
#pragma unroll 1
  for (int j = 0; j < ndiag; ++j) {
    const int kb = tile * 64 + j * 32;
    const bf16x8 k00 = KFRAG(kb + c, 0), k01 = KFRAG(kb + c, 1);
    const bf16x8 k10 = KFRAG(kb + 16 + c, 0), k11 = KFRAG(kb + 16 + c, 1);
    const bf16x8 bv0 = VFRAG(0, kb), bv1 = VFRAG(1, kb);
    const bf16x8 bv2 = VFRAG(2, kb), bv3 = VFRAG(3, kb);

    f32x4 s0 = {}, s1 = {};
    s0 = MFMA16(k00, bq0, s0);
    s0 = MFMA16(k01, bq1, s0);
    s1 = MFMA16(k10, bq0, s1);
    s1 = MFMA16(k11, bq1, s1);

    float v0[4], v1[4];
#pragma unroll
    for (int r = 0; r < 4; ++r) {
      v0[r] = (kb + g4 + r <= qc) ? s0[r] : -__builtin_inff();
      v1[r] = (kb + 16 + g4 + r <= qc) ? s1[r] : -__builtin_inff();
    }
    const float vml = fmaxf(fmaxf(fmaxf(v0[0], v0[1]), fmaxf(v0[2], v0[3])),
                            fmaxf(fmaxf(v1[0], v1[1]), fmaxf(v1[2], v1[3])));
    if (!__all(vml - m_c <= 5.0f)) {
      float vm = vml;
      vm = fmaxf(vm, __shfl_xor(vm, 16));
      vm = fmaxf(vm, __shfl_xor(vm, 32));
      const float mn = fmaxf(m_c, vm);
      const float al = exp2f(m_c - mn);
      m_c = mn;
      llp *= al;
#pragma unroll
      for (int r = 0; r < 4; ++r) {
        const float alr = __shfl(al, g4 + r);
        o[0][r] *= alr; o[1][r] *= alr; o[2][r] *= alr; o[3][r] *= alr;
      }
    }
    float p0[4], p1[4];
#pragma unroll
    for (int r = 0; r < 4; ++r) {
      p0[r] = exp2f(v0[r] - m_c);
      p1[r] = exp2f(v1[r] - m_c);
    }
    llp += ((p0[0] + p0[1]) + (p0[2] + p0[3])) +
           ((p1[0] + p1[1]) + (p1[2] + p1[3]));

    LDS_FENCE();
    ushort4 pw;
    pw.x = f2bf(p0[0]); pw.y = f2bf(p0[1]); pw.z = f2bf(p0[2]); pw.w = f2bf(p0[3]);
    *(ushort4*)&pl[w][c][g4] = pw;
    pw.x = f2bf(p1[0]); pw.y = f2bf(p1[1]); pw.z = f2bf(p1[2]); pw.w = f2bf(p1[3]);
    *(ushort4*)&pl[w][c][16 + g4] = pw;
    LDS_FENCE();
    const bf16x8 pa = *(const bf16x8*)&pl[w][c][g * 8];

    o[0] = MFMA16(pa, bv0, o[0]);
    o[1] = MFMA16(pa, bv1, o[1]);
    o[2] = MFMA16(pa, bv2, o[2]);
    o[3] = MFMA16(pa, bv3, o[3]);
  }

  // ---- finalize: reduce per-lane partial denominators across g ----
  float ll = llp;
  ll += __shfl_xor(ll, 16);
  ll += __shfl_xor(ll, 32);
  const float inv = 1.0f / ll;
#pragma unroll
  for (int r = 0; r < 4; ++r) {
    const float invr = __shfl(inv, g4 + r);
    const size_t row = (size_t)(b * 2048 + q0 + g4 + r);
#pragma unroll
    for (int dt = 0; dt < 4; ++dt)
      aout[row * 1024 + h * 64 + dt * 16 + c] = f2bf(o[dt][r] * invr);
  }
#undef KFRAG
#undef VFRAG
#undef STAGE
}

// ---------------------------------------------------------------------------
extern "C" void kernel_launch(void* const* d_in, const int* in_sizes, int n_in,
                              void* d_out, int out_size, void* d_ws, size_t ws_size,
                              hipStream_t stream) {
  const float* x = (const float*)d_in[0];      // [2,2048,1024]
  const float* wqkv = (const float*)d_in[1];   // [1024,3072]
  const float* wout = (const float*)d_in[2];   // [1024,1024]
  float* out = (float*)d_out;                  // [2,2048,1024] f32

  unsigned short* ws = (unsigned short*)d_ws;
  unsigned short* xb = ws;                                  // 4096*1024
  unsigned short* wqkvT = xb + (size_t)4096 * 1024;         // 3072*1024
  unsigned short* woutT = wqkvT + (size_t)3072 * 1024;      // 1024*1024
  unsigned short* qkv = woutT + (size_t)1024 * 1024;        // 4096*3072
  unsigned short* vT = qkv + (size_t)4096 * 3072;           // 2*1024*2048
  unsigned short* aout = vT + (size_t)2 * 1024 * 2048;      // 4096*1024

  cast_bf16_kernel<<<4096, 256, 0, stream>>>(x, xb, 4096 * 1024 / 4);
  transpose_cast_kernel<<<dim3(96, 32), dim3(32, 8), 0, stream>>>(wqkv, wqkvT, 1024, 3072, 1024);
  transpose_cast_kernel<<<dim3(32, 32), dim3(32, 8), 0, stream>>>(wout, woutT, 1024, 1024, 0);
  gemm128_kernel<1><<<dim3(24, 32), 256, 0, stream>>>(xb, wqkvT, qkv, 4096, 3072, 1024);
  transpose_v_kernel<<<dim3(32, 64, 2), dim3(32, 8), 0, stream>>>(qkv, vT);
  attn_kernel<<<1024, 256, 0, stream>>>(qkv, vT, aout);
  gemm128_kernel<0><<<dim3(8, 32), 256, 0, stream>>>(aout, woutT, out, 4096, 1024, 1024);
}

// Round 7
// 132.754 us; speedup vs baseline: 1.5944x; 1.0249x over previous
//
#include <hip/hip_runtime.h>

// Fused causal MHA: B=2, N=2048, D=1024, H=16, dh=64
// Round 7: fix round-6 OOB (P-bounce rows were 40 ushorts but KVBLK=64 path
// touched elements up to 63). Split P-bounce into two 32-col passes reusing
// the same 40-elem rows -> LDS 37.9KB -> 4 blocks/CU. Keep merged prep,
// MAX3 reduce, setprio, compiler-only WAR ordering.

typedef __bf16 bf16x8 __attribute__((ext_vector_type(8)));
typedef float f32x4 __attribute__((ext_vector_type(4)));

#define MFMA16(a, b, c) __builtin_amdgcn_mfma_f32_16x16x32_bf16((a), (b), (c), 0, 0, 0)

// Full DS drain + schedule pin (RAW/WAR cross-lane through LDS).
#define LDS_FENCE()                                   \
  do {                                                \
    asm volatile("s_waitcnt lgkmcnt(0)" ::: "memory");\
    __builtin_amdgcn_sched_barrier(0);                \
  } while (0)
// Compiler-only ordering (defeats TBAA no-alias reordering; DS pipe is
// in-order per wave so no hardware wait needed for WAR).
#define LDS_ORDER() asm volatile("" ::: "memory")

#define MAX3(a, b, c) fmaxf(fmaxf((a), (b)), (c))

__device__ __forceinline__ unsigned short f2bf(float f) {
  __bf16 h = (__bf16)f;                 // hardware RNE cvt
  return *(unsigned short*)&h;
}

// ---------------- fused prep: cast x, transpose-cast weights ----------------
// blocks 0..4095: cast x (f32->bf16, 1024 f32 each)
// blocks 4096..7167: transpose-cast wqkv [1024][3072] -> [3072][1024], Q rows scaled
// blocks 7168..8191: transpose-cast wout [1024][1024] -> [1024][1024]
__global__ __launch_bounds__(256) void prep_kernel(
    const float* __restrict__ x, const float* __restrict__ wqkv,
    const float* __restrict__ wout, unsigned short* __restrict__ xb,
    unsigned short* __restrict__ wqkvT, unsigned short* __restrict__ woutT) {
  __shared__ float tile[32][33];
  const int id = blockIdx.x, t = threadIdx.x;
  if (id < 4096) {
    const int i = id * 256 + t;
    float4 v = ((const float4*)x)[i];
    ushort4 o;
    o.x = f2bf(v.x); o.y = f2bf(v.y); o.z = f2bf(v.z); o.w = f2bf(v.w);
    ((ushort4*)xb)[i] = o;
    return;
  }
  const int tx = t & 31, ty = t >> 5;
  const float* in; unsigned short* out;
  int C, scale_rows, bx, by;
  if (id < 7168) {
    const int q = id - 4096;
    in = wqkv; out = wqkvT; C = 3072; scale_rows = 1024;
    bx = q % 96; by = q / 96;
  } else {
    const int q = id - 7168;
    in = wout; out = woutT; C = 1024; scale_rows = 0;
    bx = q & 31; by = q >> 5;
  }
#pragma unroll
  for (int i = ty; i < 32; i += 8)
    tile[i][tx] = in[(size_t)(by * 32 + i) * C + bx * 32 + tx];
  __syncthreads();
#pragma unroll
  for (int i = ty; i < 32; i += 8) {
    const int orow = bx * 32 + i;
    const float s = (orow < scale_rows) ? 0.18033688f : 1.0f;  // 0.125*log2e
    out[(size_t)orow * 1024 + by * 32 + tx] = f2bf(tile[tx][i] * s);
  }
}

// ------- transpose V region of qkv (bf16) into vT[b][h*64+dim][n] -----------
__global__ void transpose_v_kernel(const unsigned short* __restrict__ qkv,
                                   unsigned short* __restrict__ vT) {
  __shared__ unsigned short tile[32][33];
  const int b = blockIdx.z, bx = blockIdx.x, by = blockIdx.y;
  const int tx = threadIdx.x, ty = threadIdx.y;
#pragma unroll
  for (int i = ty; i < 32; i += 8)
    tile[i][tx] = qkv[(size_t)(b * 2048 + by * 32 + i) * 3072 + 2048 + bx * 32 + tx];
  __syncthreads();
#pragma unroll
  for (int i = ty; i < 32; i += 8)
    vT[((size_t)b * 1024 + bx * 32 + i) * 2048 + by * 32 + tx] = tile[tx][i];
}

// ---------------- 128x128 bf16 GEMM: C = A[M][K] * BT[Nc][K]^T --------------
template <int OUT_BF16>
__global__ __launch_bounds__(256) void gemm128_kernel(
    const unsigned short* __restrict__ A,   // [M][K] bf16
    const unsigned short* __restrict__ BT,  // [Nc][K] bf16
    void* __restrict__ Cp, int M, int Nc, int K) {
  __shared__ unsigned short lA[128 * 32];
  __shared__ unsigned short lB[128 * 32];
  const int t = threadIdx.x;
  const int l = t & 63, g = l >> 4, c = l & 15;
  const int w = t >> 6;
  const int wm = (w >> 1) * 64, wn = (w & 1) * 64;
  const int bm = blockIdx.y * 128, bn = blockIdx.x * 128;

  const int i0 = t, i1 = 256 + t;
  const unsigned short* ga0 = A + (size_t)(bm + (i0 >> 2)) * K + (i0 & 3) * 8;
  const unsigned short* ga1 = A + (size_t)(bm + (i1 >> 2)) * K + (i1 & 3) * 8;
  const unsigned short* gb0 = BT + (size_t)(bn + (i0 >> 2)) * K + (i0 & 3) * 8;
  const unsigned short* gb1 = BT + (size_t)(bn + (i1 >> 2)) * K + (i1 & 3) * 8;
  unsigned short* la0 = lA + (i0 & ~63) * 8;
  unsigned short* la1 = lA + (i1 & ~63) * 8;
  unsigned short* lb0 = lB + (i0 & ~63) * 8;
  unsigned short* lb1 = lB + (i1 & ~63) * 8;

  f32x4 acc[4][4] = {};

  for (int kk = 0; kk < K; kk += 32) {
    __syncthreads();
    __builtin_amdgcn_global_load_lds(
        (const __attribute__((address_space(1))) void*)(ga0 + kk),
        (__attribute__((address_space(3))) void*)la0, 16, 0, 0);
    __builtin_amdgcn_global_load_lds(
        (const __attribute__((address_space(1))) void*)(ga1 + kk),
        (__attribute__((address_space(3))) void*)la1, 16, 0, 0);
    __builtin_amdgcn_global_load_lds(
        (const __attribute__((address_space(1))) void*)(gb0 + kk),
        (__attribute__((address_space(3))) void*)lb0, 16, 0, 0);
    __builtin_amdgcn_global_load_lds(
        (const __attribute__((address_space(1))) void*)(gb1 + kk),
        (__attribute__((address_space(3))) void*)lb1, 16, 0, 0);
    __syncthreads();

    bf16x8 af[4], bfr[4];
#pragma unroll
    for (int mi = 0; mi < 4; ++mi)
      af[mi] = *(const bf16x8*)(lA + (wm + mi * 16 + c) * 32 + g * 8);
#pragma unroll
    for (int ni = 0; ni < 4; ++ni)
      bfr[ni] = *(const bf16x8*)(lB + (wn + ni * 16 + c) * 32 + g * 8);
#pragma unroll
    for (int mi = 0; mi < 4; ++mi)
#pragma unroll
      for (int ni = 0; ni < 4; ++ni)
        acc[mi][ni] = MFMA16(af[mi], bfr[ni], acc[mi][ni]);
  }

  if (OUT_BF16) {
    unsigned short* Cc = (unsigned short*)Cp;
#pragma unroll
    for (int mi = 0; mi < 4; ++mi)
#pragma unroll
      for (int r = 0; r < 4; ++r) {
        const int gr = bm + wm + mi * 16 + g * 4 + r;
#pragma unroll
        for (int ni = 0; ni < 4; ++ni)
          Cc[(size_t)gr * Nc + bn + wn + ni * 16 + c] = f2bf(acc[mi][ni][r]);
      }
  } else {
    float* Cf = (float*)Cp;
#pragma unroll
    for (int mi = 0; mi < 4; ++mi)
#pragma unroll
      for (int r = 0; r < 4; ++r) {
        const int gr = bm + wm + mi * 16 + g * 4 + r;
#pragma unroll
        for (int ni = 0; ni < 4; ++ni)
          Cf[(size_t)gr * Nc + bn + wn + ni * 16 + c] = acc[mi][ni][r];
      }
  }
}

// ---------------- flash attention (causal, swapped QK^T) --------------------
__global__ __launch_bounds__(256) void attn_kernel(
    const unsigned short* __restrict__ qkv,  // [4096][3072] bf16 (Q|K|V)
    const unsigned short* __restrict__ vT,   // [2][1024][2048] bf16
    unsigned short* __restrict__ aout) {     // [4096][1024] bf16
  const int t = threadIdx.x, w = t >> 6, l = t & 63, g = l >> 4, c = l & 15;
  const int g4 = g * 4, c7 = c & 7;

  // decode: xcd-clustered heads, descending tile within each XCD sequence
  const int id0 = blockIdx.x;              // 0..1023
  const int xcd = id0 & 7, pos = id0 >> 3; // pos 0..127
  const int bh = xcd * 4 + (pos & 3);      // 4 heads per XCD
  const int tile = 31 - (pos >> 2);        // big tiles first
  const int b = bh >> 4, h = bh & 15;

  __shared__ __align__(16) unsigned short lK[2][64][64];  // 16 KB
  __shared__ __align__(16) unsigned short lV[2][64][64];  // 16 KB
  __shared__ __align__(16) unsigned short pl[4][16][40];  // 5 KB P bounce (32 cols/pass)

  const unsigned short* Qbase = qkv + (size_t)b * 2048 * 3072 + h * 64;
  const unsigned short* Kb = Qbase + 1024;
  const unsigned short* Vb = vT + ((size_t)b * 1024 + h * 64) * 2048;

#define KFRAG(row, half) (*(const bf16x8*)(Kb + (size_t)(row) * 3072 + (half) * 32 + g * 8))
#define VFRAG(dt, kvoff) (*(const bf16x8*)(Vb + (size_t)((dt) * 16 + c) * 2048 + (kvoff) + g * 8))

#define STAGE(dK, dV, kb_)                                                    \
  do {                                                                        \
    _Pragma("unroll")                                                         \
    for (int q = 0; q < 2; ++q) {                                             \
      const int idx = q * 256 + t;                                            \
      const int row = idx >> 3, ch = idx & 7;                                 \
      const int sc = (ch ^ (row & 7)) * 8;                                    \
      __builtin_amdgcn_global_load_lds(                                       \
          (const __attribute__((address_space(1))) void*)(                    \
              Kb + (size_t)(kb_ + row) * 3072 + sc),                          \
          (__attribute__((address_space(3))) void*)(                          \
              &(dK)[0][0] + (idx & ~63) * 8), 16, 0, 0);                      \
      __builtin_amdgcn_global_load_lds(                                       \
          (const __attribute__((address_space(1))) void*)(                    \
              Vb + (size_t)row * 2048 + (kb_) + sc),                          \
          (__attribute__((address_space(3))) void*)(                          \
              &(dV)[0][0] + (idx & ~63) * 8), 16, 0, 0);                      \
    }                                                                         \
  } while (0)

  const int q0 = tile * 64 + w * 16;
  const int qc = q0 + c;

  const bf16x8 bq0 = *(const bf16x8*)(Qbase + (size_t)qc * 3072 + g * 8);
  const bf16x8 bq1 = *(const bf16x8*)(Qbase + (size_t)qc * 3072 + 32 + g * 8);

  f32x4 o[4] = {};
  float m_c = -__builtin_inff(), llp = 0.f;

  if (tile > 0) {
    STAGE(lK[0], lV[0], 0);
    int cur = 0;
#pragma unroll 1
    for (int jb = 0; jb < tile; ++jb) {
      __syncthreads();   // drains stage(cur) (vmcnt) + prev compute
      if (jb + 1 < tile) STAGE(lK[cur ^ 1], lV[cur ^ 1], (jb + 1) * 64);

      const unsigned short* lk = &lK[cur][0][0];
      const unsigned short* lv = &lV[cur][0][0];

      // K frags: row 16n+c, logical chunk half*4+g -> phys ^(c&7)
      bf16x8 ka[8];
#pragma unroll
      for (int n = 0; n < 4; ++n) {
        ka[2 * n]     = *(const bf16x8*)(lk + (16 * n + c) * 64 + ((g ^ c7) * 8));
        ka[2 * n + 1] = *(const bf16x8*)(lk + (16 * n + c) * 64 + (((4 + g) ^ c7) * 8));
      }
      // V frags: dim dt*16+c, logical chunk ks*4+g
      bf16x8 bv[2][4];
#pragma unroll
      for (int ks = 0; ks < 2; ++ks)
#pragma unroll
        for (int dt = 0; dt < 4; ++dt)
          bv[ks][dt] = *(const bf16x8*)(lv + (dt * 16 + c) * 64 + (((ks * 4 + g) ^ c7) * 8));

      f32x4 s[4] = {};
      __builtin_amdgcn_s_setprio(1);
#pragma unroll
      for (int n = 0; n < 4; ++n) {
        s[n] = MFMA16(ka[2 * n], bq0, s[n]);
        s[n] = MFMA16(ka[2 * n + 1], bq1, s[n]);
      }
      __builtin_amdgcn_s_setprio(0);

      // ---- softmax, mask-free fast path (exp2 domain) ----
      const float t0 = MAX3(s[0][0], s[0][1], s[0][2]);
      const float t1 = MAX3(s[0][3], s[1][0], s[1][1]);
      const float t2 = MAX3(s[1][2], s[1][3], s[2][0]);
      const float t3 = MAX3(s[2][1], s[2][2], s[2][3]);
      const float t4 = MAX3(s[3][0], s[3][1], s[3][2]);
      const float vml = fmaxf(MAX3(t0, t1, t2), MAX3(t3, t4, s[3][3]));

      if (!__all(vml - m_c <= 5.0f)) {   // rare: rescale
        float vm = vml;
        vm = fmaxf(vm, __shfl_xor(vm, 16));
        vm = fmaxf(vm, __shfl_xor(vm, 32));
        const float mn = fmaxf(m_c, vm);
        const float al = exp2f(m_c - mn);
        m_c = mn;
        llp *= al;
#pragma unroll
        for (int r = 0; r < 4; ++r) {
          const float alr = __shfl(al, g4 + r);
          o[0][r] *= alr; o[1][r] *= alr; o[2][r] *= alr; o[3][r] *= alr;
        }
      }

#pragma unroll
      for (int n = 0; n < 4; ++n)
#pragma unroll
        for (int r = 0; r < 4; ++r)
          s[n][r] = exp2f(s[n][r] - m_c);

      llp += ((s[0][0] + s[0][1]) + (s[0][2] + s[0][3])) +
             ((s[1][0] + s[1][1]) + (s[1][2] + s[1][3])) +
             ((s[2][0] + s[2][1]) + (s[2][2] + s[2][3])) +
             ((s[3][0] + s[3][1]) + (s[3][2] + s[3][3]));

      // ---- P bounce, pass 1: kv cols 0..31 ----
      LDS_ORDER();   // keep stores after prior reads (compile order)
#pragma unroll
      for (int n = 0; n < 2; ++n) {
        ushort4 pw;
        pw.x = f2bf(s[n][0]); pw.y = f2bf(s[n][1]);
        pw.z = f2bf(s[n][2]); pw.w = f2bf(s[n][3]);
        *(ushort4*)&pl[w][c][n * 16 + g4] = pw;
      }
      LDS_FENCE();   // stores visible before cross-lane read
      const bf16x8 pa0 = *(const bf16x8*)&pl[w][c][g * 8];
      // ---- P bounce, pass 2: kv cols 32..63 into the SAME slots ----
      LDS_FENCE();   // pa0 read drained before overwrite (cross-lane WAR)
#pragma unroll
      for (int n = 2; n < 4; ++n) {
        ushort4 pw;
        pw.x = f2bf(s[n][0]); pw.y = f2bf(s[n][1]);
        pw.z = f2bf(s[n][2]); pw.w = f2bf(s[n][3]);
        *(ushort4*)&pl[w][c][(n - 2) * 16 + g4] = pw;
      }
      LDS_FENCE();
      const bf16x8 pa1 = *(const bf16x8*)&pl[w][c][g * 8];

      __builtin_amdgcn_s_setprio(1);
#pragma unroll
      for (int dt = 0; dt < 4; ++dt) {
        o[dt] = MFMA16(pa0, bv[0][dt], o[dt]);
        o[dt] = MFMA16(pa1, bv[1][dt], o[dt]);
      }
      __builtin_amdgcn_s_setprio(0);
      cur ^= 1;
    }
  }

  // ---- diagonal: 1-2 masked 32-kv blocks, direct global, barrier-free ----
  const int ndiag = 1 + (w >> 1);
#pragma unroll 1
  for (int j = 0; j < ndiag; ++j) {
    const int kb = tile * 64 + j * 32;
    const bf16x8 k00 = KFRAG(kb + c, 0), k01 = KFRAG(kb + c, 1);
    const bf16x8 k10 = KFRAG(kb + 16 + c, 0), k11 = KFRAG(kb + 16 + c, 1);
    const bf16x8 bv0 = VFRAG(0, kb), bv1 = VFRAG(1, kb);
    const bf16x8 bv2 = VFRAG(2, kb), bv3 = VFRAG(3, kb);

    f32x4 s0 = {}, s1 = {};
    s0 = MFMA16(k00, bq0, s0);
    s0 = MFMA16(k01, bq1, s0);
    s1 = MFMA16(k10, bq0, s1);
    s1 = MFMA16(k11, bq1, s1);

    float v0[4], v1[4];
#pragma unroll
    for (int r = 0; r < 4; ++r) {
      v0[r] = (kb + g4 + r <= qc) ? s0[r] : -__builtin_inff();
      v1[r] = (kb + 16 + g4 + r <= qc) ? s1[r] : -__builtin_inff();
    }
    const float t0 = MAX3(v0[0], v0[1], v0[2]);
    const float t1 = MAX3(v0[3], v1[0], v1[1]);
    const float vml = fmaxf(fmaxf(t0, t1), fmaxf(v1[2], v1[3]));
    if (!__all(vml - m_c <= 5.0f)) {
      float vm = vml;
      vm = fmaxf(vm, __shfl_xor(vm, 16));
      vm = fmaxf(vm, __shfl_xor(vm, 32));
      const float mn = fmaxf(m_c, vm);
      const float al = exp2f(m_c - mn);
      m_c = mn;
      llp *= al;
#pragma unroll
      for (int r = 0; r < 4; ++r) {
        const float alr = __shfl(al, g4 + r);
        o[0][r] *= alr; o[1][r] *= alr; o[2][r] *= alr; o[3][r] *= alr;
      }
    }
    float p0[4], p1[4];
#pragma unroll
    for (int r = 0; r < 4; ++r) {
      p0[r] = exp2f(v0[r] - m_c);
      p1[r] = exp2f(v1[r] - m_c);
    }
    llp += ((p0[0] + p0[1]) + (p0[2] + p0[3])) +
           ((p1[0] + p1[1]) + (p1[2] + p1[3]));

    LDS_ORDER();
    ushort4 pw;
    pw.x = f2bf(p0[0]); pw.y = f2bf(p0[1]); pw.z = f2bf(p0[2]); pw.w = f2bf(p0[3]);
    *(ushort4*)&pl[w][c][g4] = pw;
    pw.x = f2bf(p1[0]); pw.y = f2bf(p1[1]); pw.z = f2bf(p1[2]); pw.w = f2bf(p1[3]);
    *(ushort4*)&pl[w][c][16 + g4] = pw;
    LDS_FENCE();
    const bf16x8 pa = *(const bf16x8*)&pl[w][c][g * 8];

    o[0] = MFMA16(pa, bv0, o[0]);
    o[1] = MFMA16(pa, bv1, o[1]);
    o[2] = MFMA16(pa, bv2, o[2]);
    o[3] = MFMA16(pa, bv3, o[3]);
  }

  // ---- finalize: reduce per-lane partial denominators across g ----
  float ll = llp;
  ll += __shfl_xor(ll, 16);
  ll += __shfl_xor(ll, 32);
  const float inv = 1.0f / ll;
#pragma unroll
  for (int r = 0; r < 4; ++r) {
    const float invr = __shfl(inv, g4 + r);
    const size_t row = (size_t)(b * 2048 + q0 + g4 + r);
#pragma unroll
    for (int dt = 0; dt < 4; ++dt)
      aout[row * 1024 + h * 64 + dt * 16 + c] = f2bf(o[dt][r] * invr);
  }
#undef KFRAG
#undef VFRAG
#undef STAGE
}

// ---------------------------------------------------------------------------
extern "C" void kernel_launch(void* const* d_in, const int* in_sizes, int n_in,
                              void* d_out, int out_size, void* d_ws, size_t ws_size,
                              hipStream_t stream) {
  const float* x = (const float*)d_in[0];      // [2,2048,1024]
  const float* wqkv = (const float*)d_in[1];   // [1024,3072]
  const float* wout = (const float*)d_in[2];   // [1024,1024]
  float* out = (float*)d_out;                  // [2,2048,1024] f32

  unsigned short* ws = (unsigned short*)d_ws;
  unsigned short* xb = ws;                                  // 4096*1024
  unsigned short* wqkvT = xb + (size_t)4096 * 1024;         // 3072*1024
  unsigned short* woutT = wqkvT + (size_t)3072 * 1024;      // 1024*1024
  unsigned short* qkv = woutT + (size_t)1024 * 1024;        // 4096*3072
  unsigned short* vT = qkv + (size_t)4096 * 3072;           // 2*1024*2048
  unsigned short* aout = vT + (size_t)2 * 1024 * 2048;      // 4096*1024

  prep_kernel<<<8192, 256, 0, stream>>>(x, wqkv, wout, xb, wqkvT, woutT);
  gemm128_kernel<1><<<dim3(24, 32), 256, 0, stream>>>(xb, wqkvT, qkv, 4096, 3072, 1024);
  transpose_v_kernel<<<dim3(32, 64, 2), dim3(32, 8), 0, stream>>>(qkv, vT);
  attn_kernel<<<1024, 256, 0, stream>>>(qkv, vT, aout);
  gemm128_kernel<0><<<dim3(8, 32), 256, 0, stream>>>(aout, woutT, out, 4096, 1024, 1024);
}